// Round 8
// baseline (332.236 us; speedup 1.0000x reference)
//
#include <hip/hip_runtime.h>

#define Nq 300
#define Tq 12
#define Dq 64
#define Mq 16
#define BTq 384
#define DDq (Dq*Dq)      // 4096
#define Fq (Dq*3)        // 192
#define NP 320           // padded k-extent of transposed bf16 buffers

typedef short bf8_t __attribute__((ext_vector_type(8)));
typedef float f4_t  __attribute__((ext_vector_type(4)));

__device__ __forceinline__ unsigned short f2bf(float f) {
    unsigned u = __float_as_uint(f);
    u = (u + 0x7FFFu + ((u >> 16) & 1u)) >> 16;
    return (unsigned short)u;
}
__device__ __forceinline__ float bf2f(unsigned short u) {
    return __uint_as_float((unsigned)u << 16);
}
__device__ __forceinline__ float4 ld4(const float* p) { return *(const float4*)p; }

__device__ __forceinline__ bf8_t pack8(float4 a, float4 b) {
    bf8_t r;
    r[0] = (short)f2bf(a.x); r[1] = (short)f2bf(a.y);
    r[2] = (short)f2bf(a.z); r[3] = (short)f2bf(a.w);
    r[4] = (short)f2bf(b.x); r[5] = (short)f2bf(b.y);
    r[6] = (short)f2bf(b.z); r[7] = (short)f2bf(b.w);
    return r;
}

__device__ __forceinline__ float gatef(float p) {
    float pc = fminf(fmaxf(p, -30.f), 30.f);
    float sig = __fdividef(1.f, 1.f + __expf(-pc));
    float e2  = __expf(2.f * pc);
    float th  = __fdividef(e2 - 1.f, e2 + 1.f);
    return sig * th;
}

// ---- Merged front-end: 1932 blocks.
//  [0,400)      ABt tiles (MFMA-C-tiled alpha/beta pairs)
//  [400,700)    Wt per-node weights (n = vb-400)
//  [700,780)    adjWb/adjBp padding
//  [780,1164)   X transpose -> Xp_t, Xp_nb
//  [1164,1548)  te -> te_b bf16 [bt][300][64]
//  [1548,1932)  zero H1_t pad cols 300..319
__global__ void __launch_bounds__(256) kprep_all(
    const float* __restrict__ a1, const float* __restrict__ a2,
    const float* __restrict__ b1, const float* __restrict__ b2,
    const float* __restrict__ w1, const float* __restrict__ w2,
    const float* __restrict__ adjW, const float* __restrict__ adjB,
    const float* __restrict__ X, const float* __restrict__ te,
    unsigned* __restrict__ ABt, unsigned short* __restrict__ Wt,
    unsigned short* __restrict__ adjWb, float* __restrict__ adjBp,
    unsigned short* __restrict__ Xp_t, unsigned short* __restrict__ Xp_nb,
    unsigned short* __restrict__ te_b, unsigned short* __restrict__ H1_t)
{
    __shared__ char smem[64 * 308 * 2];    // 39424 B union
    const int vb = blockIdx.x;
    const int tid = threadIdx.x;

    if (vb < 400) {
        const int tile = vb;
        const int reg = tid & 3, lane = tid >> 2;
        const int nt = tile % 5;  int r1 = tile / 5;
        const int w  = r1 % 4;    int r2 = r1 / 4;
        const int c  = r2 % 5;    const int qi = r2 / 5;
        const int n = qi*80 + nt*16 + (lane & 15);
        const int k = c*64 + w*16 + (lane >> 4)*4 + reg;
        unsigned outv = 0u;
        if (n < Nq && k < Nq) {
            float sa = 0.f, sb = 0.f;
            #pragma unroll
            for (int m = 0; m < Mq; ++m) {
                sa = fmaf(a1[n*Mq+m], a2[m*Nq+k], sa);
                sb = fmaf(b1[n*Mq+m], b2[m*Nq+k], sb);
            }
            outv = ((unsigned)f2bf(sb) << 16) | (unsigned)f2bf(sa);
        }
        ABt[tile*256 + tid] = outv;
    } else if (vb < 700) {
        float* sT = (float*)smem;          // [64][65]
        __shared__ float sw1[Mq];
        const int n = vb - 400;
        if (tid < Mq) sw1[tid] = w1[n*Mq + tid];
        __syncthreads();
        for (int i = tid; i < DDq; i += 256) {
            int k = i >> 6, d = i & 63;
            float s = 0.f;
            #pragma unroll
            for (int m = 0; m < Mq; ++m) s = fmaf(sw1[m], w2[m*DDq + i], s);
            sT[d*65 + k] = s;
        }
        __syncthreads();
        for (int i = tid; i < DDq; i += 256) {
            int d = i >> 6, k = i & 63;
            Wt[(size_t)n*DDq + i] = f2bf(sT[d*65 + k]);
        }
    } else if (vb < 780) {
        int e = (vb - 700) * 256 + tid;
        if (e < NP * 64) {
            int k = e >> 6, d = e & 63;
            adjWb[e] = (k < Nq) ? f2bf(adjW[k*Dq + d]) : (unsigned short)0;
        }
        if (e < NP) adjBp[e] = (e < Nq) ? adjB[e] : 0.f;
    } else if (vb < 1164) {
        unsigned short* sT = (unsigned short*)smem;   // [64][308]
        const int bx = vb - 780;
        const int b = bx / 12, tile = bx % 12;
        const int n0 = tile * 25;
        for (int i = tid; i < 64 * 300; i += 256) {
            int d = i / 300, j = i - d * 300;
            sT[d*308 + j] = f2bf(X[(size_t)(b*64 + d)*3600 + n0*12 + j]);
        }
        __syncthreads();
        for (int wi = tid; wi < 12 * 64 * 25; wi += 256) {
            int nl = wi % 25, rem = wi / 25;
            int d = rem % 64, t = rem / 64;
            Xp_t[((size_t)(b*Tq + t)*64 + d)*NP + n0 + nl] = sT[d*308 + nl*12 + t];
        }
        if (tile == 11) {
            for (int wi = tid; wi < 12 * 64 * 20; wi += 256) {
                int e = wi % 20, rem = wi / 20;
                int d = rem % 64, t = rem / 64;
                Xp_t[((size_t)(b*Tq + t)*64 + d)*NP + 300 + e] = 0;
            }
        }
        for (int wi = tid; wi < 25 * 12 * 64; wi += 256) {
            int d = wi & 63, rem = wi >> 6;
            int t = rem % 12, nl = rem / 12;
            Xp_nb[((size_t)(n0 + nl)*BTq + b*Tq + t)*64 + d] = sT[d*308 + nl*12 + t];
        }
    } else if (vb < 1548) {
        const int bt = vb - 1164;
        const int b = bt / Tq, t = bt - b * Tq;
        for (int i = tid; i < 300 * 32; i += 256) {   // float2 -> packed bf16 pair
            int n = i >> 5, dp = (i & 31) * 2;
            const float* s = te + (((size_t)b*Nq + n)*Tq + t)*Dq + dp;
            unsigned lo = f2bf(s[0]), hi = f2bf(s[1]);
            *(unsigned*)&te_b[((size_t)bt*Nq + n)*Dq + dp] = lo | (hi << 16);
        }
    } else {
        const int bt = vb - 1548;
        for (int i = tid; i < 64 * 20; i += 256) {
            int d = i / 20, e = i % 20;
            H1_t[((size_t)bt*64 + d)*NP + 300 + e] = 0;
        }
    }
}

// Fused A-recompute + aggregation, single-barrier version.
// grid 1536 = (bt, n-quarter of 80); LDS: full P tile [80][328] bf16 = 52480 B.
__global__ void __launch_bounds__(256) kfuse(
    const unsigned short* __restrict__ te_b,   // [bt][300][64]
    const unsigned short* __restrict__ adjWb,  // [320][64]
    const float* __restrict__ adjBp,           // [320]
    const unsigned* __restrict__ ABt,          // tiled pairs
    const unsigned short* __restrict__ Hb_t,   // [bt][64][320]
    unsigned short* __restrict__ Hout_nb)      // [300][384][64]
{
    __shared__ unsigned short sPl[80 * 328];
    const int bt = blockIdx.x >> 2, qi = blockIdx.x & 3;
    const int nbase = qi * 80;
    const int tid = threadIdx.x;
    const int w = tid >> 6, lane = tid & 63, quad = lane >> 4, l16 = lane & 15;
    const int drow = w*16 + l16;

    // hoisted te B-frags for GEMM1 (lane = n)
    bf8_t tb0[5], tb1[5];
    #pragma unroll
    for (int nt = 0; nt < 5; ++nt) {
        int n = nbase + nt*16 + l16; if (n > Nq-1) n = Nq-1;
        const unsigned short* r = te_b + ((size_t)bt*Nq + n)*64;
        tb0[nt] = *(const bf8_t*)(r + quad*8);
        tb1[nt] = *(const bf8_t*)(r + 32 + quad*8);
    }
    // hoisted Hb A-frags for GEMM2 (lane = d) — in flight during GEMM1
    bf8_t hb0[5], hb1[5];
    const unsigned short* hbase = Hb_t + ((size_t)bt*64 + drow)*NP;
    #pragma unroll
    for (int c = 0; c < 5; ++c) {
        hb0[c] = *(const bf8_t*)(hbase + c*64 + quad*8);
        hb1[c] = *(const bf8_t*)(hbase + c*64 + 32 + quad*8);
    }

    // ---- GEMM1: P^T[k][n] = adjW @ te^T, epilogue sin/scale/relu, store P to LDS
    #pragma unroll
    for (int c = 0; c < 5; ++c) {
        const int cbase = c * 64;
        const unsigned short* ar = adjWb + (cbase + w*16 + l16)*64;
        bf8_t ka0 = *(const bf8_t*)(ar + quad*8);
        bf8_t ka1 = *(const bf8_t*)(ar + 32 + quad*8);
        float4 bias4 = ld4(adjBp + cbase + w*16 + quad*4);
        const unsigned* abbase = ABt + ((((size_t)qi*5 + c)*4 + w)*5)*256 + lane*4;
        #pragma unroll
        for (int nt = 0; nt < 5; ++nt) {
            f4_t p = {0.f, 0.f, 0.f, 0.f};
            p = __builtin_amdgcn_mfma_f32_16x16x32_bf16(ka0, tb0[nt], p, 0, 0, 0);
            p = __builtin_amdgcn_mfma_f32_16x16x32_bf16(ka1, tb1[nt], p, 0, 0, 0);
            uint4 ab = *(const uint4*)(abbase + nt*256);
            ushort4 o4;
            {
                float sv = __sinf(p[0] + bias4.x);
                o4.x = f2bf(fmaxf(fmaf(__uint_as_float(ab.x << 16), sv,
                                       __uint_as_float(ab.x & 0xFFFF0000u)), 0.f));
            }
            {
                float sv = __sinf(p[1] + bias4.y);
                o4.y = f2bf(fmaxf(fmaf(__uint_as_float(ab.y << 16), sv,
                                       __uint_as_float(ab.y & 0xFFFF0000u)), 0.f));
            }
            {
                float sv = __sinf(p[2] + bias4.z);
                o4.z = f2bf(fmaxf(fmaf(__uint_as_float(ab.z << 16), sv,
                                       __uint_as_float(ab.z & 0xFFFF0000u)), 0.f));
            }
            {
                float sv = __sinf(p[3] + bias4.w);
                o4.w = f2bf(fmaxf(fmaf(__uint_as_float(ab.w << 16), sv,
                                       __uint_as_float(ab.w & 0xFFFF0000u)), 0.f));
            }
            *(ushort4*)&sPl[(nt*16 + l16)*328 + cbase + w*16 + quad*4] = o4;
        }
    }
    __syncthreads();   // the only barrier

    // ---- GEMM2 (swapped: C^T, rows=d): O^T[d][n] += Hb^T @ P^T
    f4_t accO[5];
    #pragma unroll
    for (int rt = 0; rt < 5; ++rt) accO[rt] = (f4_t){0.f, 0.f, 0.f, 0.f};
    #pragma unroll
    for (int c = 0; c < 5; ++c) {
        #pragma unroll
        for (int rt = 0; rt < 5; ++rt) {
            bf8_t p0 = *(const bf8_t*)&sPl[(rt*16 + l16)*328 + c*64 + quad*8];
            bf8_t p1 = *(const bf8_t*)&sPl[(rt*16 + l16)*328 + c*64 + 32 + quad*8];
            accO[rt] = __builtin_amdgcn_mfma_f32_16x16x32_bf16(hb0[c], p0, accO[rt], 0, 0, 0);
            accO[rt] = __builtin_amdgcn_mfma_f32_16x16x32_bf16(hb1[c], p1, accO[rt], 0, 0, 0);
        }
    }
    // epilogue: lane owns (n = nbase+rt*16+l16, d = w*16+quad*4+0..3) -> ushort4 store
    #pragma unroll
    for (int rt = 0; rt < 5; ++rt) {
        int ng = nbase + rt*16 + l16;
        if (ng < Nq) {
            ushort4 o;
            o.x = f2bf(accO[rt][0]); o.y = f2bf(accO[rt][1]);
            o.z = f2bf(accO[rt][2]); o.w = f2bf(accO[rt][3]);
            *(ushort4*)&Hout_nb[((size_t)ng*BTq + bt)*64 + w*16 + quad*4] = o;
        }
    }
}

// Per-node matmul + gate (swapped: C^T rows=d). grid 1200 = (n, bt-quarter of 96).
// Writes Hout_nb vectorized; optionally also Ht [bt][64][320] (hop-1, replaces ktr2).
// In-place safe (hop-2): all Hagg reads complete before barrier.
__global__ void __launch_bounds__(256) kmm(
    const unsigned short* __restrict__ Hagg_nb,  // [n][384][64]
    const unsigned short* __restrict__ Xp_nb,    // [n][384][64]
    const unsigned short* __restrict__ Wt,       // [n][64][64]
    unsigned short* __restrict__ Hout_nb,        // [n][384][64]
    unsigned short* __restrict__ Ht)             // [bt][64][320] or nullptr
{
    const int n = blockIdx.x >> 2, qi = blockIdx.x & 3;
    const int bt0 = qi * 96;
    const int tid = threadIdx.x;
    const int w = tid >> 6, lane = tid & 63, quad = lane >> 4, l16 = lane & 15;
    const unsigned short* wn = Wt + (size_t)n * DDq + (w*16 + l16)*64;
    bf8_t a0 = *(const bf8_t*)(wn + quad*8);
    bf8_t a1 = *(const bf8_t*)(wn + 32 + quad*8);
    f4_t acc[6];
    #pragma unroll
    for (int rt = 0; rt < 6; ++rt) acc[rt] = (f4_t){0.f, 0.f, 0.f, 0.f};
    #pragma unroll
    for (int rt = 0; rt < 6; ++rt) {
        int r = bt0 + rt*16 + l16;
        const unsigned short* row = Hagg_nb + ((size_t)n*BTq + r)*64;
        bf8_t b0 = *(const bf8_t*)(row + quad*8);
        bf8_t b1 = *(const bf8_t*)(row + 32 + quad*8);
        acc[rt] = __builtin_amdgcn_mfma_f32_16x16x32_bf16(a0, b0, acc[rt], 0, 0, 0);
        acc[rt] = __builtin_amdgcn_mfma_f32_16x16x32_bf16(a1, b1, acc[rt], 0, 0, 0);
    }
    __syncthreads();
    const int dbase = w*16 + quad*4;
    #pragma unroll
    for (int rt = 0; rt < 6; ++rt) {
        int r = bt0 + rt*16 + l16;
        size_t idx = ((size_t)n*BTq + r)*64 + dbase;
        ushort4 xp4 = *(const ushort4*)&Xp_nb[idx];
        ushort4 o;
        o.x = f2bf(gatef(bf2f(xp4.x) + acc[rt][0]));
        o.y = f2bf(gatef(bf2f(xp4.y) + acc[rt][1]));
        o.z = f2bf(gatef(bf2f(xp4.z) + acc[rt][2]));
        o.w = f2bf(gatef(bf2f(xp4.w) + acc[rt][3]));
        *(ushort4*)&Hout_nb[idx] = o;
        if (Ht) {
            Ht[((size_t)r*64 + dbase + 0)*NP + n] = o.x;
            Ht[((size_t)r*64 + dbase + 1)*NP + n] = o.y;
            Ht[((size_t)r*64 + dbase + 2)*NP + n] = o.z;
            Ht[((size_t)r*64 + dbase + 3)*NP + n] = o.w;
        }
    }
}

// GCN epilogue. grid 1216 = (b, n-tile 16, r-half of 96).
__global__ void __launch_bounds__(256) kgcn(
    const unsigned short* __restrict__ Xp_nb, const unsigned short* __restrict__ H1_nb,
    const unsigned short* __restrict__ H2_nb, const float* __restrict__ gcnW,
    const float* __restrict__ gcnB, float* __restrict__ out)
{
    const int bx = blockIdx.x;
    const int half = bx & 1;
    const int bt19 = bx >> 1;
    const int b = bt19 / 19, tile = bt19 % 19;
    const int n0 = tile * 16;
    const int rows = (tile == 18) ? 144 : 192;
    const int tid = threadIdx.x;
    const int w = tid >> 6, lane = tid & 63, quad = lane >> 4, l16 = lane & 15;
    const int dcol = w*16 + l16;
    const float bias = gcnB[dcol];
    f4_t acc[6];
    #pragma unroll
    for (int rt = 0; rt < 6; ++rt) acc[rt] = (f4_t){0.f, 0.f, 0.f, 0.f};
    const unsigned short* bufs[3] = {Xp_nb, H1_nb, H2_nb};
    #pragma unroll
    for (int c = 0; c < 3; ++c) {
        const unsigned short* buf = bufs[c];
        const float* gwr = gcnW + (size_t)dcol*Fq + c*Dq;
        bf8_t v0 = pack8(ld4(gwr + quad*8),      ld4(gwr + quad*8 + 4));
        bf8_t v1 = pack8(ld4(gwr + 32 + quad*8), ld4(gwr + 36 + quad*8));
        #pragma unroll
        for (int rt = 0; rt < 6; ++rt) {
            int r = half*96 + rt*16 + l16;
            int nl = r / 12, t = r - nl*12;
            int n = n0 + nl; if (n > Nq-1) n = Nq-1;
            const unsigned short* row = buf + ((size_t)n*BTq + b*Tq + t)*64;
            bf8_t a0 = *(const bf8_t*)(row + quad*8);
            bf8_t a1 = *(const bf8_t*)(row + 32 + quad*8);
            acc[rt] = __builtin_amdgcn_mfma_f32_16x16x32_bf16(a0, v0, acc[rt], 0, 0, 0);
            acc[rt] = __builtin_amdgcn_mfma_f32_16x16x32_bf16(a1, v1, acc[rt], 0, 0, 0);
        }
    }
    float* outd = out + (size_t)(b*Dq + dcol)*3600 + n0*12;
    #pragma unroll
    for (int rt = 0; rt < 6; ++rt) {
        int ra = half*96 + rt*16;
        if (ra < rows) {
            int r0 = ra + quad*4;
            float4 o = make_float4(acc[rt][0] + bias, acc[rt][1] + bias,
                                   acc[rt][2] + bias, acc[rt][3] + bias);
            *(float4*)&outd[r0] = o;
        }
    }
}

extern "C" void kernel_launch(void* const* d_in, const int* in_sizes, int n_in,
                              void* d_out, int out_size, void* d_ws, size_t ws_size,
                              hipStream_t stream) {
    (void)in_sizes; (void)n_in; (void)out_size; (void)ws_size;
    const float* X    = (const float*)d_in[0];
    const float* te   = (const float*)d_in[1];
    const float* adjW = (const float*)d_in[2];
    const float* adjB = (const float*)d_in[3];
    const float* w1   = (const float*)d_in[4];
    const float* w2   = (const float*)d_in[5];
    const float* a1   = (const float*)d_in[6];
    const float* a2   = (const float*)d_in[7];
    const float* b1   = (const float*)d_in[8];
    const float* b2   = (const float*)d_in[9];
    const float* gW   = (const float*)d_in[10];
    const float* gB   = (const float*)d_in[11];
    float* out = (float*)d_out;

    char* ws = (char*)d_ws;
    unsigned*       ABt    = (unsigned*)      (ws);               //    409,600
    unsigned short* adjWb  = (unsigned short*)(ws + 409600);      //  +  40,960 =    450,560
    float*          adjBp  = (float*)         (ws + 450560);      //  +   1,280 =    451,840
    unsigned short* Wt     = (unsigned short*)(ws + 451840);      //  +2,457,600 =  2,909,440
    unsigned short* te_b   = (unsigned short*)(ws + 2909440);     // +14,745,600 = 17,655,040
    unsigned short* Xp_t   = (unsigned short*)(ws + 17655040);    // +15,728,640 = 33,383,680
    unsigned short* Xp_nb  = (unsigned short*)(ws + 33383680);    // +14,745,600 = 48,129,280
    unsigned short* Hagg   = (unsigned short*)(ws + 48129280);    // +14,745,600 = 62,874,880
    unsigned short* H1_nb  = (unsigned short*)(ws + 62874880);    // +14,745,600 = 77,620,480
    unsigned short* H1_t   = (unsigned short*)(ws + 77620480);    // +15,728,640 = 93,349,120 B

    hipLaunchKernelGGL(kprep_all, dim3(1932), dim3(256), 0, stream,
                       a1, a2, b1, b2, w1, w2, adjW, adjB, X, te,
                       ABt, Wt, adjWb, adjBp, Xp_t, Xp_nb, te_b, H1_t);
    // hop 1
    hipLaunchKernelGGL(kfuse, dim3(1536), dim3(256), 0, stream, te_b, adjWb, adjBp, ABt, Xp_t, Hagg);
    hipLaunchKernelGGL(kmm,   dim3(1200), dim3(256), 0, stream, Hagg, Xp_nb, Wt, H1_nb, H1_t);
    // hop 2
    hipLaunchKernelGGL(kfuse, dim3(1536), dim3(256), 0, stream, te_b, adjWb, adjBp, ABt, H1_t, Hagg);
    hipLaunchKernelGGL(kmm,   dim3(1200), dim3(256), 0, stream, Hagg, Xp_nb, Wt, Hagg,
                       (unsigned short*)nullptr); // in-place -> H2
    // gcn epilogue
    hipLaunchKernelGGL(kgcn,  dim3(1216), dim3(256), 0, stream, Xp_nb, H1_nb, Hagg, gW, gB, out);
}